// Round 1
// baseline (238.630 us; speedup 1.0000x reference)
//
#include <hip/hip_runtime.h>
#include <hip/hip_bf16.h>

// ConvEmbedding: out[b,t,c] = bias[c] + sum_k W[c, x[b,t+k-4], k]
// B=8, T=4096, H=512, V=32000, K=9.
//
// Phase 1: transpose+convert W (H, V*K) f32 -> Wt (V*K, H) bf16 in d_ws,
//          i.e. layout (V, K, H): per-token row of K*H bf16 = 9216 B contiguous.
//          Extra zero row at id==V implements the zero padding at sequence edges.
// Phase 2: gather: per (b, t-tile) block, stage token ids (+halo) in LDS,
//          each thread owns 2 channels, 9 coalesced row-slice reads per t.

#define Hc 512
#define Vc 32000
#define Kc 9
#define Tc 4096
#define Bc 8
#define Mc (Vc * Kc)          // 288000 (m = v*K + k)
#define ROWU ((Kc * Hc) / 2)  // 2304 uints per Wt token row
#define T_TILE 32

__device__ __forceinline__ unsigned short f2bf(float f) {
  unsigned int u = __float_as_uint(f);
  u += 0x7FFFu + ((u >> 16) & 1u);   // round-to-nearest-even
  return (unsigned short)(u >> 16);
}

// W[c][m] -> Wt[m][c] with f32 -> bf16. 64x64 tiles, 256 threads.
__global__ __launch_bounds__(256) void wt_transpose_kernel(
    const float* __restrict__ in, unsigned short* __restrict__ out) {
  __shared__ float tile[64][65];
  const int m0 = blockIdx.x * 64;
  const int c0 = blockIdx.y * 64;
  const int tx = threadIdx.x & 63;
  const int ty = threadIdx.x >> 6;  // 0..3
#pragma unroll
  for (int r = 0; r < 16; ++r) {
    const int row = ty * 16 + r;  // 0..63 (c offset)
    tile[row][tx] = in[(size_t)(c0 + row) * Mc + (m0 + tx)];
  }
  __syncthreads();
#pragma unroll
  for (int r = 0; r < 16; ++r) {
    const int mrow = ty * 16 + r;  // 0..63 (m offset)
    out[(size_t)(m0 + mrow) * Hc + (c0 + tx)] = f2bf(tile[tx][mrow]);
  }
}

// Gather: grid = B * (T/T_TILE) blocks, 256 threads (each owns 2 channels).
__global__ __launch_bounds__(256) void conv_gather_kernel(
    const int* __restrict__ x, const unsigned int* __restrict__ Wt,
    const float* __restrict__ bias, float* __restrict__ out) {
  __shared__ int ids[T_TILE + Kc - 1];  // source positions t0-4 .. t0+T_TILE+3
  const int blk = blockIdx.x;
  const int b = blk >> 7;               // T/T_TILE = 128 tiles per batch
  const int t0 = (blk & 127) * T_TILE;
  const int tid = threadIdx.x;
  if (tid < T_TILE + Kc - 1) {
    const int s = t0 + tid - (Kc / 2);
    ids[tid] = (s >= 0 && s < Tc) ? x[b * Tc + s] : Vc;  // Vc -> zero row
  }
  __syncthreads();
  const float2 b2 = *(const float2*)(bias + 2 * tid);
  float2* out2 = (float2*)out;
  for (int tt = 0; tt < T_TILE; ++tt) {
    float2 acc = b2;
#pragma unroll
    for (int k = 0; k < Kc; ++k) {
      const int id = ids[tt + k];
      const unsigned int w = Wt[(size_t)id * ROWU + k * (Hc / 2) + tid];
      acc.x += __uint_as_float(w << 16);
      acc.y += __uint_as_float(w & 0xFFFF0000u);
    }
    out2[(size_t)(b * Tc + t0 + tt) * (Hc / 2) + tid] = acc;
  }
}

// Fallback (ws too small): direct, slow but correct.
__global__ __launch_bounds__(256) void conv_fallback_kernel(
    const int* __restrict__ x, const float* __restrict__ W,
    const float* __restrict__ bias, float* __restrict__ out) {
  const size_t idx = (size_t)blockIdx.x * 256 + threadIdx.x;  // (b*T+t)*H + c
  const int c = (int)(idx & (Hc - 1));
  const size_t bt = idx >> 9;
  const int t = (int)(bt & (Tc - 1));
  const int b = (int)(bt >> 12);
  float acc = bias[c];
#pragma unroll
  for (int k = 0; k < Kc; ++k) {
    const int s = t + k - (Kc / 2);
    if (s >= 0 && s < Tc) {
      const int id = x[b * Tc + s];
      acc += W[(size_t)c * Mc + (size_t)id * Kc + k];
    }
  }
  out[idx] = acc;
}

extern "C" void kernel_launch(void* const* d_in, const int* in_sizes, int n_in,
                              void* d_out, int out_size, void* d_ws, size_t ws_size,
                              hipStream_t stream) {
  const int* x = (const int*)d_in[0];
  const float* W = (const float*)d_in[1];
  const float* bias = (const float*)d_in[2];
  float* out = (float*)d_out;

  const size_t wt_bytes = (size_t)(Vc + 1) * Kc * Hc * 2;  // 294,921,216 B
  if (ws_size >= wt_bytes) {
    unsigned short* Wt = (unsigned short*)d_ws;
    // zero row for out-of-range positions (id == V)
    hipMemsetAsync(Wt + (size_t)Vc * Kc * Hc, 0, (size_t)Kc * Hc * 2, stream);
    dim3 g1(Mc / 64, Hc / 64);  // 4500 x 8
    wt_transpose_kernel<<<g1, 256, 0, stream>>>(W, Wt);
    conv_gather_kernel<<<Bc * (Tc / T_TILE), 256, 0, stream>>>(
        x, (const unsigned int*)Wt, bias, out);
  } else {
    const size_t n = (size_t)Bc * Tc * Hc;
    conv_fallback_kernel<<<(int)(n / 256), 256, 0, stream>>>(x, W, bias, out);
  }
}

// Round 2
// 234.796 us; speedup vs baseline: 1.0163x; 1.0163x over previous
//
#include <hip/hip_runtime.h>
#include <hip/hip_bf16.h>

// ConvEmbedding: out[b,t,c] = bias[c] + sum_k W[c, x[b,t+k-4], k]
// B=8, T=4096, H=512, V=32000, K=9.
//
// R2: compact Wt to touched tokens (~20.3K of 32K -> ~188 MB, fits 256 MB L3),
//     uint-packed transpose writes, slot table via atomicCAS+counter.
// Pipeline: memset(slot=-1, counter=0, zero-row) -> mark -> transpose(compact)
//           -> gather.

#define Hc 512
#define Vc 32000
#define Kc 9
#define Tc 4096
#define Bc 8
#define Mc (Vc * Kc)          // 288000 (m = v*K + k)
#define ROWU ((Kc * Hc) / 2)  // 2304 uints per Wt token row (9216 B)
#define T_TILE 32
#define WT_ROWS (Vc + 1)      // worst case: all tokens unique + zero row

__device__ __forceinline__ unsigned short f2bf(float f) {
  unsigned int u = __float_as_uint(f);
  u += 0x7FFFu + ((u >> 16) & 1u);   // round-to-nearest-even
  return (unsigned short)(u >> 16);
}

// Assign compact slots to touched vocab ids. slot[] pre-set to -1, counter=0.
// Slot 0 is reserved for the zero row (sequence-boundary padding).
__global__ __launch_bounds__(256) void mark_kernel(
    const int* __restrict__ x, int* __restrict__ slot, int* __restrict__ counter) {
  const int i = blockIdx.x * 256 + threadIdx.x;  // B*T = 32768 threads
  const int v = x[i];
  if (atomicCAS(&slot[v], -1, -2147483647) == -1) {
    slot[v] = 1 + atomicAdd(counter, 1);
  }
}

// W[c][m] -> Wt[slot[m/9]][ (m%9)*256 + c/2 ] packed bf16x2, touched rows only.
// 64x64 tiles, 256 threads.
__global__ __launch_bounds__(256) void wt_transpose_kernel(
    const float* __restrict__ in, unsigned int* __restrict__ outu,
    const int* __restrict__ slot) {
  __shared__ float tile[64][65];
  const int m0 = blockIdx.x * 64;
  const int c0 = blockIdx.y * 64;
  const int tx = threadIdx.x & 63;
  const int ty = threadIdx.x >> 6;  // 0..3
#pragma unroll
  for (int r = 0; r < 16; ++r) {
    const int row = ty * 16 + r;  // c offset 0..63
    tile[row][tx] = in[(size_t)(c0 + row) * Mc + (m0 + tx)];
  }
  __syncthreads();
  // write phase: 8 passes; per pass 256 threads cover 8 m-rows x 32 uints
  const int u = threadIdx.x & 31;   // uint (channel-pair) index within tile
  const int rl = threadIdx.x >> 5;  // 0..7
#pragma unroll
  for (int p = 0; p < 8; ++p) {
    const int mrow = p * 8 + rl;    // 0..63
    const int m = m0 + mrow;
    const int v = m / Kc;
    const int k = m - v * Kc;
    const int s = slot[v];
    if (s >= 0) {
      const unsigned int val = (unsigned int)f2bf(tile[2 * u][mrow]) |
                               ((unsigned int)f2bf(tile[2 * u + 1][mrow]) << 16);
      outu[(size_t)s * ROWU + k * (Hc / 2) + (c0 >> 1) + u] = val;
    }
  }
}

// Gather: grid = B * (T/T_TILE) blocks, 256 threads (each owns 2 channels).
__global__ __launch_bounds__(256) void conv_gather_kernel(
    const int* __restrict__ x, const unsigned int* __restrict__ Wt,
    const int* __restrict__ slot, const float* __restrict__ bias,
    float* __restrict__ out) {
  __shared__ int ids[T_TILE + Kc - 1];  // compact slot ids for t0-4 .. t0+35
  const int blk = blockIdx.x;
  const int b = blk >> 7;               // T/T_TILE = 128 tiles per batch
  const int t0 = (blk & 127) * T_TILE;
  const int tid = threadIdx.x;
  if (tid < T_TILE + Kc - 1) {
    const int s = t0 + tid - (Kc / 2);
    ids[tid] = (s >= 0 && s < Tc) ? slot[x[b * Tc + s]] : 0;  // 0 -> zero row
  }
  __syncthreads();
  const float2 b2 = *(const float2*)(bias + 2 * tid);
  float2* out2 = (float2*)out;
  for (int tt = 0; tt < T_TILE; ++tt) {
    float2 acc = b2;
#pragma unroll
    for (int k = 0; k < Kc; ++k) {
      const int id = ids[tt + k];
      const unsigned int w = Wt[(size_t)id * ROWU + k * (Hc / 2) + tid];
      acc.x += __uint_as_float(w << 16);
      acc.y += __uint_as_float(w & 0xFFFF0000u);
    }
    out2[(size_t)(b * Tc + t0 + tt) * (Hc / 2) + tid] = acc;
  }
}

// Fallback (ws too small): direct, slow but correct.
__global__ __launch_bounds__(256) void conv_fallback_kernel(
    const int* __restrict__ x, const float* __restrict__ W,
    const float* __restrict__ bias, float* __restrict__ out) {
  const size_t idx = (size_t)blockIdx.x * 256 + threadIdx.x;  // (b*T+t)*H + c
  const int c = (int)(idx & (Hc - 1));
  const size_t bt = idx >> 9;
  const int t = (int)(bt & (Tc - 1));
  const int b = (int)(bt >> 12);
  float acc = bias[c];
#pragma unroll
  for (int k = 0; k < Kc; ++k) {
    const int s = t + k - (Kc / 2);
    if (s >= 0 && s < Tc) {
      const int id = x[b * Tc + s];
      acc += W[(size_t)c * Mc + (size_t)id * Kc + k];
    }
  }
  out[idx] = acc;
}

extern "C" void kernel_launch(void* const* d_in, const int* in_sizes, int n_in,
                              void* d_out, int out_size, void* d_ws, size_t ws_size,
                              hipStream_t stream) {
  const int* x = (const int*)d_in[0];
  const float* W = (const float*)d_in[1];
  const float* bias = (const float*)d_in[2];
  float* out = (float*)d_out;

  const size_t wt_bytes = (size_t)WT_ROWS * ROWU * 4;      // 294,930,432 B
  const size_t slot_off = wt_bytes;                        // 32000 ints
  const size_t cnt_off = slot_off + (size_t)Vc * 4;        // 1 int
  const size_t need = cnt_off + 4;

  if (ws_size >= need) {
    unsigned int* Wt = (unsigned int*)d_ws;
    int* slot = (int*)((char*)d_ws + slot_off);
    int* counter = (int*)((char*)d_ws + cnt_off);
    hipMemsetAsync(slot, 0xFF, (size_t)Vc * 4, stream);    // slot[v] = -1
    hipMemsetAsync(counter, 0, 4, stream);                 // counter = 0
    hipMemsetAsync(Wt, 0, (size_t)Kc * Hc * 2, stream);    // zero row (slot 0)
    mark_kernel<<<(Bc * Tc) / 256, 256, 0, stream>>>(x, slot, counter);
    dim3 g1(Mc / 64, Hc / 64);  // 4500 x 8
    wt_transpose_kernel<<<g1, 256, 0, stream>>>(W, Wt, slot);
    conv_gather_kernel<<<Bc * (Tc / T_TILE), 256, 0, stream>>>(
        x, Wt, slot, bias, out);
  } else {
    const size_t n = (size_t)Bc * Tc * Hc;
    conv_fallback_kernel<<<(int)(n / 256), 256, 0, stream>>>(x, W, bias, out);
  }
}